// Round 2
// baseline (228.927 us; speedup 1.0000x reference)
//
#include <hip/hip_runtime.h>

// DenSparse: out[b, dst_e] += w_e * x[b, src_e]
// B=32, IN=OUT=65536, NNZ=1048576
//
// Round 2 strategy: counting-sort edges by dst, then accumulate each dst's
// edge list in registers (32 batch lanes per dst) with NO float atomics.
// Round-1 counters showed WRITE_SIZE == nnz*128B: every f32 atomicAdd was
// written through to the fabric (device-scope), 16x write amplification.

#define IN_SIZE  65536
#define OUT_SIZE 65536
#define BATCH    32

// ---------------- generic zero ----------------
__global__ void zero_f4(float4* __restrict__ p, int n4) {
    int i = blockIdx.x * blockDim.x + threadIdx.x;
    if (i < n4) p[i] = make_float4(0.f, 0.f, 0.f, 0.f);
}

// ---------------- x[32][IN] -> x_t[IN][32] ----------------
__global__ void transpose_in(const float* __restrict__ x, float* __restrict__ xt) {
    __shared__ float tile[32][33];
    int i0 = blockIdx.x * 32;
    int tx = threadIdx.x & 31;
    int ty = threadIdx.x >> 5;
    tile[ty][tx] = x[(size_t)ty * IN_SIZE + i0 + tx];
    __syncthreads();
    xt[((size_t)(i0 + ty)) * BATCH + tx] = tile[tx][ty];
}

// ---------------- histogram of dst ----------------
__global__ void hist_dst(const int4* __restrict__ dst4, int* __restrict__ cnt, int n4) {
    int i = blockIdx.x * blockDim.x + threadIdx.x;
    if (i < n4) {
        int4 d = dst4[i];
        atomicAdd(&cnt[d.x], 1);
        atomicAdd(&cnt[d.y], 1);
        atomicAdd(&cnt[d.z], 1);
        atomicAdd(&cnt[d.w], 1);
    }
}

// ---------------- single-WG exclusive scan of 64K counts ----------------
// 1024 threads, 64 counts each. cnt lives in `cur` (overwritten with start
// offsets for the reorder pass); exclusive offsets also written to `offs`
// (65537 entries, offs[65536] = nnz).
__global__ void scan_counts(int* __restrict__ cur, int* __restrict__ offs) {
    __shared__ int sums[1024];
    const int tid = threadIdx.x;
    const int base = tid * 64;
    // local sum of 64 counts (16 x int4)
    int lsum = 0;
    const int4* c4 = (const int4*)(cur + base);
    #pragma unroll
    for (int j = 0; j < 16; ++j) {
        int4 v = c4[j];
        lsum += v.x + v.y + v.z + v.w;
    }
    sums[tid] = lsum;
    __syncthreads();
    // Hillis-Steele inclusive scan over 1024 thread sums
    for (int ofs = 1; ofs < 1024; ofs <<= 1) {
        int v = (tid >= ofs) ? sums[tid - ofs] : 0;
        __syncthreads();
        sums[tid] += v;
        __syncthreads();
    }
    int running = sums[tid] - lsum;  // exclusive base for this thread's range
    // second pass: write exclusive offsets, overwrite cur with start offsets
    #pragma unroll
    for (int j = 0; j < 16; ++j) {
        int4 v = c4[j];
        int idx = base + j * 4;
        offs[idx + 0] = running; int r0 = running + v.x;
        offs[idx + 1] = r0;      int r1 = r0 + v.y;
        offs[idx + 2] = r1;      int r2 = r1 + v.z;
        offs[idx + 3] = r2;      running = r2 + v.w;
        // overwrite counts with start offsets (cursor for reorder)
        ((int4*)(cur + base))[j] = make_int4(offs[idx], r0, r1, r2);
    }
    if (tid == 1023) offs[OUT_SIZE] = running;  // == nnz
}

// ---------------- reorder edges into dst-sorted order ----------------
__global__ void reorder_edges(const int* __restrict__ dst,
                              const int* __restrict__ src,
                              const float* __restrict__ w,
                              int* __restrict__ cur,
                              unsigned short* __restrict__ s16,
                              float* __restrict__ ws,
                              int nnz) {
    int e = blockIdx.x * blockDim.x + threadIdx.x;
    if (e < nnz) {
        int d = dst[e];
        int pos = atomicAdd(&cur[d], 1);
        s16[pos] = (unsigned short)src[e];
        ws[pos]  = w[e];
    }
}

// ---------------- accumulate per dst + fused transpose ----------------
// Block = 1024 threads = 32 half-waves; half-wave hw handles dst d0+hw,
// lane b handles batch b. No atomics; one coalesced 32x32 tile write.
__global__ void accum_csr(const float* __restrict__ xt,
                          const unsigned short* __restrict__ s16,
                          const float* __restrict__ ws,
                          const int* __restrict__ offs,
                          float* __restrict__ out) {
    __shared__ float tile[32][33];
    int d0 = blockIdx.x * 32;
    int hw = threadIdx.x >> 5;
    int b  = threadIdx.x & 31;
    int d  = d0 + hw;
    int beg = offs[d];
    int end = offs[d + 1];
    float acc = 0.f;
    for (int i = beg; i < end; ++i) {
        int   s  = s16[i];   // broadcast across 32 lanes
        float wv = ws[i];    // broadcast
        acc += wv * xt[s * BATCH + b];   // one 128B line per edge
    }
    tile[hw][b] = acc;
    __syncthreads();
    int tx = threadIdx.x & 31;
    int ty = threadIdx.x >> 5;
    out[(size_t)ty * OUT_SIZE + d0 + tx] = tile[tx][ty];
}

// ---------------- fallback: direct atomic scatter ----------------
__global__ void scatter_direct(const float* __restrict__ x,
                               const float* __restrict__ w,
                               const int*   __restrict__ dst,
                               const int*   __restrict__ src,
                               float*       __restrict__ out,
                               int nnz) {
    int t = blockIdx.x * blockDim.x + threadIdx.x;
    int e = t >> 5;
    int b = t & 31;
    if (e < nnz) {
        atomicAdd(&out[(size_t)b * OUT_SIZE + dst[e]],
                  w[e] * x[(size_t)b * IN_SIZE + src[e]]);
    }
}

extern "C" void kernel_launch(void* const* d_in, const int* in_sizes, int n_in,
                              void* d_out, int out_size, void* d_ws, size_t ws_size,
                              hipStream_t stream) {
    const float* x   = (const float*)d_in[0];   // [32][65536]
    const float* w   = (const float*)d_in[1];   // [NNZ]
    const int*   dst = (const int*)d_in[2];     // [NNZ]
    const int*   src = (const int*)d_in[3];     // [NNZ]
    float*       out = (float*)d_out;           // [32][65536]
    const int nnz = in_sizes[1];

    // workspace layout (15 MiB total)
    const size_t XT_OFF    = 0;                          // 8 MiB
    const size_t OFFS_OFF  = (size_t)8  << 20;           // 65537 ints (~256KB)
    const size_t CUR_OFF   = ((size_t)8 << 20) + ((size_t)512 << 10); // 256 KB
    const size_t S16_OFF   = (size_t)9  << 20;           // 2 MiB
    const size_t W_OFF     = (size_t)11 << 20;           // 4 MiB
    const size_t WS_NEEDED = (size_t)15 << 20;

    if (ws_size >= WS_NEEDED) {
        float*          xt   = (float*)((char*)d_ws + XT_OFF);
        int*            offs = (int*)  ((char*)d_ws + OFFS_OFF);
        int*            cur  = (int*)  ((char*)d_ws + CUR_OFF);
        unsigned short* s16  = (unsigned short*)((char*)d_ws + S16_OFF);
        float*          ws   = (float*)((char*)d_ws + W_OFF);

        // 1. zero counters (cur doubles as cnt)
        zero_f4<<<(OUT_SIZE / 4 + 255) / 256, 256, 0, stream>>>((float4*)cur, OUT_SIZE / 4);
        // 2. transpose x -> xt (independent of 3-5)
        transpose_in<<<IN_SIZE / 32, 1024, 0, stream>>>(x, xt);
        // 3. histogram dst
        hist_dst<<<(nnz / 4 + 255) / 256, 256, 0, stream>>>((const int4*)dst, cur, nnz / 4);
        // 4. scan -> offs (exclusive), cur = start offsets
        scan_counts<<<1, 1024, 0, stream>>>(cur, offs);
        // 5. reorder edges by dst
        reorder_edges<<<(nnz + 255) / 256, 256, 0, stream>>>(dst, src, w, cur, s16, ws, nnz);
        // 6. accumulate + fused transpose (writes every output element)
        accum_csr<<<OUT_SIZE / 32, 1024, 0, stream>>>(xt, s16, ws, offs, out);
    } else {
        // fallback: zero d_out, atomics in native layout
        int n4 = out_size / 4;
        zero_f4<<<(n4 + 255) / 256, 256, 0, stream>>>((float4*)d_out, n4);
        long long total = (long long)nnz * 32;
        int blocks = (int)((total + 255) / 256);
        scatter_direct<<<blocks, 256, 0, stream>>>(x, w, dst, src, out, nnz);
    }
}